// Round 1
// baseline (15827.875 us; speedup 1.0000x reference)
//
#include <hip/hip_runtime.h>

// SimpleRNN (B=64,T=256,I=128,H=1024,L=3,O=2) — persistent pipelined MFMA kernel.
//
// Strategy:
//  - prep kernel: zero flag counters; build fused bias; split x and all weights
//    into bf16 (hi, lo) pairs in d_ws. Weight matrices are concatenated
//    [Wx | Wh] along K so each layer is one GEMM: C[64, 1024] = A[64,K] * W[1024,K]^T,
//    K = 1152 (layer 0) / 2048 (layers 1,2).
//  - pipeline kernel: 192 blocks x 256 thr. block -> (layer, colgroup of 64 n,
//    k-quarter). Weights staged to LDS ONCE (hi+lo, padded rows), reused all 256
//    steps. Per step: 3-pass split-bf16 MFMA (hh + hl + lh => ~2^-17 relative
//    accuracy, safe vs fp32 tolerance), fp32 partials; last-arriving k-block
//    reduces + bias + tanh + writes h (bf16 hi/lo) and releases a ready flag.
//    Producer/consumer flags (agent-scope acquire/release atomics) give a
//    wavefront pipeline across layers with NO grid barriers. 8-deep h ring with
//    done-counter back-pressure. Block 0 computes the final FC in fp32.
//  - Residency: 133 KB dynamic LDS/block => exactly 1 block/CU, 192 <= 256 CUs,
//    so all blocks are resident; spin-waits cannot deadlock.

typedef __attribute__((ext_vector_type(8))) short short8;
typedef __attribute__((ext_vector_type(4))) float float4v;
typedef __attribute__((ext_vector_type(4))) unsigned short ushort4v;

#define DEVFN static __device__ __forceinline__

DEVFN unsigned short f2bf(float f) {           // fp32 -> bf16 bits, RNE
  unsigned int u = __float_as_uint(f);
  u += 0x7FFFu + ((u >> 16) & 1u);
  return (unsigned short)(u >> 16);
}
DEVFN float bf2f(unsigned short h) { return __uint_as_float(((unsigned int)h) << 16); }

namespace rnncfg {
constexpr int  BB = 64, TT = 256, II = 128, HH = 1024;
constexpr long WELEMS = 1024L * 1152 + 2L * 1024 * 2048;   // 5,373,952 (concat W, all layers)
constexpr long XELEMS = (long)BB * TT * II;                // 2,097,152
constexpr long HELEMS = 3L * 8 * BB * HH;                  // h ring: 3 layers x 8 slots
constexpr long PELEMS = 3L * 16 * 4 * BB * 64;             // partials: (l,cg,ks) x [64][64]

constexpr long OFF_WHI  = 0;
constexpr long OFF_WLO  = OFF_WHI + WELEMS * 2;
constexpr long OFF_XHI  = OFF_WLO + WELEMS * 2;
constexpr long OFF_XLO  = OFF_XHI + XELEMS * 2;
constexpr long OFF_HHI  = OFF_XLO + XELEMS * 2;
constexpr long OFF_HLO  = OFF_HHI + HELEMS * 2;
constexpr long OFF_PART = OFF_HLO + HELEMS * 2;
constexpr long OFF_BIAS = OFF_PART + PELEMS * 4;
constexpr long OFF_CNT  = OFF_BIAS + 3L * HH * 4;
constexpr long N_CNT    = 768 + 768 + 12288;               // READY, DONE, ARR
constexpr long WS_NEED  = OFF_CNT + N_CNT * 4;             // ~37.6 MB

constexpr int SMEM_BYTES = 2 * 64 * (512 + 8) * 2;         // hi+lo, 64 rows, padded: 133,120 B
}

__global__ __launch_bounds__(256) void rnn_prep_kernel(
    const float* __restrict__ x,
    const float* __restrict__ wx0, const float* __restrict__ bx0,
    const float* __restrict__ wh0, const float* __restrict__ bh0,
    const float* __restrict__ wx,  const float* __restrict__ bx,
    const float* __restrict__ wh,  const float* __restrict__ bh,
    char* __restrict__ ws)
{
  using namespace rnncfg;
  unsigned short* WHI = (unsigned short*)(ws + OFF_WHI);
  unsigned short* WLO = (unsigned short*)(ws + OFF_WLO);
  unsigned short* XHI = (unsigned short*)(ws + OFF_XHI);
  unsigned short* XLO = (unsigned short*)(ws + OFF_XLO);
  float* BIAS = (float*)(ws + OFF_BIAS);
  int*   CNT  = (int*)(ws + OFF_CNT);
  const long i0 = (long)blockIdx.x * blockDim.x + threadIdx.x;
  const long st = (long)gridDim.x * blockDim.x;

  for (long i = i0; i < N_CNT; i += st) CNT[i] = 0;   // ws is 0xAA-poisoned: must zero flags

  for (long i = i0; i < 3 * HH; i += st) {            // fused bias = bx + bh
    int l = (int)(i >> 10), n = (int)(i & 1023);
    BIAS[i] = (l == 0) ? (bx0[n] + bh0[n]) : (bx[(l - 1) * HH + n] + bh[(l - 1) * HH + n]);
  }
  for (long i = i0; i < XELEMS; i += st) {            // x -> bf16 hi/lo
    float v = x[i];
    unsigned short h = f2bf(v);
    XHI[i] = h; XLO[i] = f2bf(v - bf2f(h));
  }
  for (long i = i0; i < WELEMS; i += st) {            // concat [Wx|Wh] -> bf16 hi/lo
    long j = i; int n, k; float v;
    if (j < 1179648L) {                               // layer 0: [1024][1152]
      n = (int)(j / 1152); k = (int)(j % 1152);
      v = (k < 128) ? wx0[n * 128 + k] : wh0[(long)n * 1024 + (k - 128)];
    } else if (j < 3276800L) {                        // layer 1: [1024][2048]
      j -= 1179648L; n = (int)(j / 2048); k = (int)(j % 2048);
      v = (k < 1024) ? wx[(long)n * 1024 + k] : wh[(long)n * 1024 + (k - 1024)];
    } else {                                          // layer 2: [1024][2048]
      j -= 3276800L; n = (int)(j / 2048); k = (int)(j % 2048);
      v = (k < 1024) ? wx[1048576L + (long)n * 1024 + k]
                     : wh[1048576L + (long)n * 1024 + (k - 1024)];
    }
    unsigned short h = f2bf(v);
    WHI[i] = h; WLO[i] = f2bf(v - bf2f(h));
  }
}

__global__ __launch_bounds__(256, 1) void rnn_pipeline_kernel(
    char* __restrict__ ws, const float* __restrict__ fcw,
    const float* __restrict__ fcb, float* __restrict__ out)
{
  using namespace rnncfg;
  extern __shared__ char smem[];
  const int tid = threadIdx.x, bid = blockIdx.x;

  // XCD-aware mapping (bid%8 = XCD on MI355X): the 4 k-split partners of a
  // (layer, colgroup) share an XCD so partial exchange stays in one L2.
  const int xcd = bid & 7, s = bid >> 3;
  const int layer = s >> 3, jj = s & 7;
  const int cg = xcd * 2 + (jj >> 2), ks = jj & 3;    // cg in [0,16), ks in [0,4)
  const int Kl = (layer == 0) ? 1152 : 2048;
  const int kslice = Kl >> 2;
  const int kbeg = ks * kslice;
  const int n0 = cg * 64;
  const int rowE = kslice + 8;                        // +8 bf16 pad: 2-way banks only (free)
  const long lwoff = (layer == 0) ? 0L : ((layer == 1) ? 1179648L : 3276800L);

  const unsigned short* WHI = (const unsigned short*)(ws + OFF_WHI);
  const unsigned short* WLO = (const unsigned short*)(ws + OFF_WLO);
  const unsigned short* XHI = (const unsigned short*)(ws + OFF_XHI);
  const unsigned short* XLO = (const unsigned short*)(ws + OFF_XLO);
  unsigned short* HHI = (unsigned short*)(ws + OFF_HHI);
  unsigned short* HLO = (unsigned short*)(ws + OFF_HLO);
  float* PART = (float*)(ws + OFF_PART);
  const float* BIAS = (const float*)(ws + OFF_BIAS);
  int* READY = (int*)(ws + OFF_CNT);                  // [3][256], 16 finishers each
  int* DONE  = READY + 768;                           // [3][256], 64 gemm blocks each
  int* ARR   = DONE + 768;                            // [3][16][256], 4 k-blocks each

  unsigned short* ldsHI = (unsigned short*)smem;
  unsigned short* ldsLO = ldsHI + 64 * rowE;

  {  // Stage this block's weight slice (64 cols x kslice, hi+lo) into LDS once.
    const int cpr = kslice >> 3;
    const long wbase = lwoff + (long)n0 * Kl + kbeg;
    for (int c = tid; c < 64 * cpr; c += 256) {
      const int row = c / cpr, cc = (c % cpr) * 8;
      *(short8*)(ldsHI + row * rowE + cc) = *(const short8*)(WHI + wbase + (long)row * Kl + cc);
      *(short8*)(ldsLO + row * rowE + cc) = *(const short8*)(WLO + wbase + (long)row * Kl + cc);
    }
  }
  __syncthreads();

  const int lane = tid & 63, wv = tid >> 6;
  const int rowb = lane & 15;                 // A-frag / B-frag row within 16
  const int kof  = (lane >> 4) * 8;           // A/B frag k offset
  const int bglob = wv * 16 + rowb;           // this lane's A batch row (wave = 1 M-tile)
  const int crow  = wv * 16 + (lane >> 4) * 4;// C row base: row=(lane>>4)*4+reg
  float* myPart = PART + ((long)((layer * 16 + cg) * 4 + ks)) * 4096;
  __shared__ int sFlag;

  for (int t = 0; t < TT; ++t) {
    // ---- waits (producer flags). Self-wait also guarantees our previous
    // partials were consumed before we overwrite them.
    if (tid == 0) {
      if (t > 0)
        while (__hip_atomic_load(&READY[layer * 256 + t - 1], __ATOMIC_ACQUIRE,
                                 __HIP_MEMORY_SCOPE_AGENT) < 16)
          __builtin_amdgcn_s_sleep(1);
      if (layer > 0 && kbeg < 1024)   // only k-slices that read h_below need it
        while (__hip_atomic_load(&READY[(layer - 1) * 256 + t], __ATOMIC_ACQUIRE,
                                 __HIP_MEMORY_SCOPE_AGENT) < 16)
          __builtin_amdgcn_s_sleep(1);
    }
    __syncthreads();

    // ---- GEMM: 3-pass split-bf16 MFMA over this k-slice
    float4v acc[4];
#pragma unroll
    for (int nt = 0; nt < 4; ++nt) acc[nt] = (float4v){0.f, 0.f, 0.f, 0.f};

    for (int kk = kbeg; kk < kbeg + kslice; kk += 32) {
      const unsigned short *pHI, *pLO;
      bool valid = true;
      if (layer == 0) {
        if (kk < 128) {                                   // x_t slice
          const long o = ((long)bglob * TT + t) * II + kk + kof;
          pHI = XHI + o; pLO = XLO + o;
        } else if (t == 0) { valid = false; pHI = pLO = nullptr; }  // h_{-1}=0
        else {
          const long o = ((long)(((t - 1) & 7) * 64 + bglob)) * 1024 + (kk - 128) + kof;
          pHI = HHI + o; pLO = HLO + o;
        }
      } else {
        if (kk < 1024) {                                  // h_below at t
          const long o = ((long)(((layer - 1) * 8 + (t & 7)) * 64 + bglob)) * 1024 + kk + kof;
          pHI = HHI + o; pLO = HLO + o;
        } else if (t == 0) { valid = false; pHI = pLO = nullptr; }
        else {                                            // h_self at t-1
          const long o = ((long)(layer * 8 + ((t - 1) & 7)) * 64 + bglob) * 1024 + (kk - 1024) + kof;
          pHI = HHI + o; pLO = HLO + o;
        }
      }
      if (!valid) continue;
      const short8 ahi = *(const short8*)pHI;
      const short8 alo = *(const short8*)pLO;
      const int kl = kk - kbeg + kof;
#pragma unroll
      for (int nt = 0; nt < 4; ++nt) {
        const short8 bhi = *(const short8*)(ldsHI + (nt * 16 + rowb) * rowE + kl);
        const short8 blo = *(const short8*)(ldsLO + (nt * 16 + rowb) * rowE + kl);
        acc[nt] = __builtin_amdgcn_mfma_f32_16x16x32_bf16(ahi, bhi, acc[nt], 0, 0, 0);
        acc[nt] = __builtin_amdgcn_mfma_f32_16x16x32_bf16(ahi, blo, acc[nt], 0, 0, 0);
        acc[nt] = __builtin_amdgcn_mfma_f32_16x16x32_bf16(alo, bhi, acc[nt], 0, 0, 0);
      }
    }

    // ---- write fp32 partial [64 b][64 n]; C layout: row=(lane>>4)*4+r, col=lane&15
#pragma unroll
    for (int nt = 0; nt < 4; ++nt)
#pragma unroll
      for (int r = 0; r < 4; ++r)
        myPart[(crow + r) * 64 + nt * 16 + (lane & 15)] = acc[nt][r];
    __syncthreads();   // drains vmem before the flags below

    if (tid == 0) {
      __hip_atomic_fetch_add(&DONE[layer * 256 + t], 1, __ATOMIC_RELEASE,
                             __HIP_MEMORY_SCOPE_AGENT);
      const int prev = __hip_atomic_fetch_add(&ARR[(layer * 16 + cg) * 256 + t], 1,
                                              __ATOMIC_ACQ_REL, __HIP_MEMORY_SCOPE_AGENT);
      sFlag = (prev == 3);                     // last arriver becomes finisher
    }
    __syncthreads();

    if (sFlag) {
      // back-pressure: h slot (t & 7) last held h[t-8]; its only possibly-lagging
      // readers are layer+1's blocks at t-8 (same-layer readers are provably done).
      if (tid == 0 && layer < 2 && t >= 8)
        while (__hip_atomic_load(&DONE[(layer + 1) * 256 + t - 8], __ATOMIC_ACQUIRE,
                                 __HIP_MEMORY_SCOPE_AGENT) < 64)
          __builtin_amdgcn_s_sleep(1);
      __syncthreads();

      const float* P0 = PART + ((long)((layer * 16 + cg) * 4)) * 4096;
      unsigned short* dHI = HHI + ((long)(layer * 8 + (t & 7))) * 64 * 1024;
      unsigned short* dLO = HLO + ((long)(layer * 8 + (t & 7))) * 64 * 1024;
#pragma unroll
      for (int e = 0; e < 4; ++e) {
        const int f = tid * 16 + e * 4;
        const int bb = f >> 6, nn = f & 63;
        float4v sv = *(const float4v*)(P0 + f);
        sv += *(const float4v*)(P0 + 4096 + f);
        sv += *(const float4v*)(P0 + 8192 + f);
        sv += *(const float4v*)(P0 + 12288 + f);
        ushort4v vhi, vlo;
#pragma unroll
        for (int c = 0; c < 4; ++c) {
          float v = sv[c] + BIAS[layer * 1024 + n0 + nn + c];
          v = tanhf(v);
          const unsigned short hh = f2bf(v);
          vhi[c] = hh; vlo[c] = f2bf(v - bf2f(hh));
        }
        const long o = ((long)bb) * 1024 + n0 + nn;
        *(ushort4v*)(dHI + o) = vhi;
        *(ushort4v*)(dLO + o) = vlo;
      }
      __syncthreads();
      if (tid == 0)
        __hip_atomic_fetch_add(&READY[layer * 256 + t], 1, __ATOMIC_RELEASE,
                               __HIP_MEMORY_SCOPE_AGENT);
    }
  }

  // ---- final FC (fp32) by block 0 after layer 2, t=255 is ready
  if (bid == 0) {
    if (tid == 0)
      while (__hip_atomic_load(&READY[2 * 256 + 255], __ATOMIC_ACQUIRE,
                               __HIP_MEMORY_SCOPE_AGENT) < 16)
        __builtin_amdgcn_s_sleep(1);
    __syncthreads();
    if (tid < 128) {
      const int bb = tid >> 1, o = tid & 1;
      const unsigned short* hH = HHI + ((long)(2 * 8 + 7)) * 64 * 1024 + (long)bb * 1024;
      const unsigned short* hL = HLO + ((long)(2 * 8 + 7)) * 64 * 1024 + (long)bb * 1024;
      float sum = fcb[o];
      for (int n = 0; n < 1024; ++n)
        sum += (bf2f(hH[n]) + bf2f(hL[n])) * fcw[o * 1024 + n];
      out[bb * 2 + o] = sum;
    }
  }
}

extern "C" void kernel_launch(void* const* d_in, const int* in_sizes, int n_in,
                              void* d_out, int out_size, void* d_ws, size_t ws_size,
                              hipStream_t stream)
{
  using namespace rnncfg;
  const float* x   = (const float*)d_in[0];
  const float* wx0 = (const float*)d_in[1];
  const float* bx0 = (const float*)d_in[2];
  const float* wh0 = (const float*)d_in[3];
  const float* bh0 = (const float*)d_in[4];
  const float* wx  = (const float*)d_in[5];
  const float* bx  = (const float*)d_in[6];
  const float* wh  = (const float*)d_in[7];
  const float* bh  = (const float*)d_in[8];
  const float* fcw = (const float*)d_in[9];
  const float* fcb = (const float*)d_in[10];
  char* ws = (char*)d_ws;
  float* out = (float*)d_out;

  if (ws_size < (size_t)WS_NEED) return;   // need ~38 MB scratch

  // >64 KB dynamic LDS requires the attribute (idempotent, capture-safe).
  hipFuncSetAttribute(reinterpret_cast<const void*>(rnn_pipeline_kernel),
                      hipFuncAttributeMaxDynamicSharedMemorySize, SMEM_BYTES);

  rnn_prep_kernel<<<dim3(1024), dim3(256), 0, stream>>>(
      x, wx0, bx0, wh0, bh0, wx, bx, wh, bh, ws);
  rnn_pipeline_kernel<<<dim3(192), dim3(256), SMEM_BYTES, stream>>>(
      ws, fcw, fcb, out);
}

// Round 3
// 7730.704 us; speedup vs baseline: 2.0474x; 2.0474x over previous
//
#include <hip/hip_runtime.h>

// SimpleRNN (B=64,T=256,I=128,H=1024,L=3,O=2) — persistent pipelined MFMA kernel, v3.
//
// v1 post-mortem: 15.8 ms, MfmaUtil 1.3%, 2.36 GB HBM/dispatch. Cause: ACQUIRE
// (L1/L2-invalidate) on EVERY spin poll + two-hop finisher through memory.
// v2 (unmeasured): block = (layer, 16-col group), full K in LDS, relaxed spins
// with a single acquire per stage, single release per stage.
// v3 = v2 + MFMA ILP fix: at 1 wave/SIMD there is no TLP, and a single
// accumulator made 192 MFMAs one serial dependency chain (~3.2 us/stage on the
// recurrence critical path). Six independent chains (3 split passes x 2-way k
// interleave) make the inner loop issue-bound (~0.9 us/stage).
// Plus: spin staleness insurance (1 acquire poll per 256 relaxed polls).

typedef __attribute__((ext_vector_type(8))) short short8;
typedef __attribute__((ext_vector_type(4))) float float4v;

#define DEVFN static __device__ __forceinline__

DEVFN unsigned short f2bf(float f) {           // fp32 -> bf16 bits, RNE
  unsigned int u = __float_as_uint(f);
  u += 0x7FFFu + ((u >> 16) & 1u);
  return (unsigned short)(u >> 16);
}
DEVFN float bf2f(unsigned short h) { return __uint_as_float(((unsigned int)h) << 16); }

DEVFN void spin_ge(int* p, int want) {         // relaxed spin + rare acquire insurance
  int it = 0;
  while (__hip_atomic_load(p, __ATOMIC_RELAXED, __HIP_MEMORY_SCOPE_AGENT) < want) {
    __builtin_amdgcn_s_sleep(1);
    if ((++it & 255) == 0 &&
        __hip_atomic_load(p, __ATOMIC_ACQUIRE, __HIP_MEMORY_SCOPE_AGENT) >= want)
      break;
  }
}

namespace rnncfg {
constexpr int  BB = 64, TT = 256, II = 128, HH = 1024;
constexpr long WELEMS = 1024L * 1152 + 2L * 1024 * 2048;   // concat [Wx|Wh], 3 layers
constexpr long XELEMS = (long)BB * TT * II;
constexpr long HELEMS = 3L * 8 * BB * HH;                  // h ring: 3 layers x 8 slots

constexpr long OFF_WHI  = 0;
constexpr long OFF_WLO  = OFF_WHI + WELEMS * 2;
constexpr long OFF_XHI  = OFF_WLO + WELEMS * 2;
constexpr long OFF_XLO  = OFF_XHI + XELEMS * 2;
constexpr long OFF_HHI  = OFF_XLO + XELEMS * 2;
constexpr long OFF_HLO  = OFF_HHI + HELEMS * 2;
constexpr long OFF_BIAS = OFF_HLO + HELEMS * 2;
constexpr long OFF_CNT  = OFF_BIAS + 3L * HH * 4;
constexpr long N_CNT    = 768;                             // READY[3][256]
constexpr long WS_NEED  = OFF_CNT + N_CNT * 4;             // ~36.2 MB

constexpr int ROWE = 2048 + 8;                             // padded K row (bf16 elems)
constexpr int SMEM_BYTES = 2 * 16 * ROWE * 2;              // hi+lo, 16 rows: 131,584 B
}

__global__ __launch_bounds__(256) void rnn_prep_kernel(
    const float* __restrict__ x,
    const float* __restrict__ wx0, const float* __restrict__ bx0,
    const float* __restrict__ wh0, const float* __restrict__ bh0,
    const float* __restrict__ wx,  const float* __restrict__ bx,
    const float* __restrict__ wh,  const float* __restrict__ bh,
    char* __restrict__ ws)
{
  using namespace rnncfg;
  unsigned short* WHI = (unsigned short*)(ws + OFF_WHI);
  unsigned short* WLO = (unsigned short*)(ws + OFF_WLO);
  unsigned short* XHI = (unsigned short*)(ws + OFF_XHI);
  unsigned short* XLO = (unsigned short*)(ws + OFF_XLO);
  float* BIAS = (float*)(ws + OFF_BIAS);
  int*   CNT  = (int*)(ws + OFF_CNT);
  const long i0 = (long)blockIdx.x * blockDim.x + threadIdx.x;
  const long st = (long)gridDim.x * blockDim.x;

  for (long i = i0; i < N_CNT; i += st) CNT[i] = 0;   // ws is 0xAA-poisoned

  for (long i = i0; i < 3 * HH; i += st) {            // fused bias = bx + bh
    int l = (int)(i >> 10), n = (int)(i & 1023);
    BIAS[i] = (l == 0) ? (bx0[n] + bh0[n]) : (bx[(l - 1) * HH + n] + bh[(l - 1) * HH + n]);
  }
  for (long i = i0; i < XELEMS; i += st) {            // x -> bf16 hi/lo
    float v = x[i];
    unsigned short h = f2bf(v);
    XHI[i] = h; XLO[i] = f2bf(v - bf2f(h));
  }
  for (long i = i0; i < WELEMS; i += st) {            // concat [Wx|Wh] -> bf16 hi/lo
    long j = i; int n, k; float v;
    if (j < 1179648L) {                               // layer 0: [1024][1152]
      n = (int)(j / 1152); k = (int)(j % 1152);
      v = (k < 128) ? wx0[n * 128 + k] : wh0[(long)n * 1024 + (k - 128)];
    } else if (j < 3276800L) {                        // layer 1: [1024][2048]
      j -= 1179648L; n = (int)(j / 2048); k = (int)(j % 2048);
      v = (k < 1024) ? wx[(long)n * 1024 + k] : wh[(long)n * 1024 + (k - 1024)];
    } else {                                          // layer 2: [1024][2048]
      j -= 3276800L; n = (int)(j / 2048); k = (int)(j % 2048);
      v = (k < 1024) ? wx[1048576L + (long)n * 1024 + k]
                     : wh[1048576L + (long)n * 1024 + (k - 1024)];
    }
    unsigned short h = f2bf(v);
    WHI[i] = h; WLO[i] = f2bf(v - bf2f(h));
  }
}

__global__ __launch_bounds__(256, 1) void rnn_pipeline_kernel(
    char* __restrict__ ws, const float* __restrict__ fcw,
    const float* __restrict__ fcb, float* __restrict__ out)
{
  using namespace rnncfg;
  extern __shared__ char smem[];
  const int tid = threadIdx.x, bid = blockIdx.x;

  const int layer = bid >> 6;              // 64 blocks per layer
  const int cg    = bid & 63;              // 16-col group
  const int n0    = cg * 16;
  const int Kl    = (layer == 0) ? 1152 : 2048;
  const int rowE  = Kl + 8;                // +8 bf16 pad keeps b128 slots spread
  const long lwoff = (layer == 0) ? 0L : ((layer == 1) ? 1179648L : 3276800L);

  const unsigned short* WHI = (const unsigned short*)(ws + OFF_WHI);
  const unsigned short* WLO = (const unsigned short*)(ws + OFF_WLO);
  const unsigned short* XHI = (const unsigned short*)(ws + OFF_XHI);
  const unsigned short* XLO = (const unsigned short*)(ws + OFF_XLO);
  unsigned short* HHI = (unsigned short*)(ws + OFF_HHI);
  unsigned short* HLO = (unsigned short*)(ws + OFF_HLO);
  const float* BIAS = (const float*)(ws + OFF_BIAS);
  int* READY = (int*)(ws + OFF_CNT);       // [3][256], 64 producers each

  unsigned short* ldsHI = (unsigned short*)smem;
  unsigned short* ldsLO = ldsHI + 16 * rowE;

  {  // Stage this block's 16 weight rows (full K, hi+lo) into LDS once.
    const int cpr = Kl >> 3;                           // short8 chunks per row
    const long wbase = lwoff + (long)n0 * Kl;
    for (int c = tid; c < 16 * cpr; c += 256) {
      const int row = c / cpr, cc = (c % cpr) * 8;
      *(short8*)(ldsHI + row * rowE + cc) = *(const short8*)(WHI + wbase + (long)row * Kl + cc);
      *(short8*)(ldsLO + row * rowE + cc) = *(const short8*)(WLO + wbase + (long)row * Kl + cc);
    }
  }
  __syncthreads();

  const int lane = tid & 63, wv = tid >> 6;
  const int rowb = lane & 15;                  // A batch row in tile / C col in tile
  const int kof  = (lane >> 4) * 8;            // frag k offset
  const int bglob = wv * 16 + rowb;            // A batch row (wave = one 16-row M-tile)
  const int crow  = wv * 16 + (lane >> 4) * 4; // C row base: row=(lane>>4)*4+r
  const float bcol = BIAS[layer * 1024 + n0 + rowb];   // bias for this lane's C col

  // 6 independent MFMA chains: 3 split passes x 2-way k interleave. At 1
  // wave/SIMD a single chain is latency-bound (~17 cy/MFMA dependent); 6 chains
  // make the loop issue-bound. All LEN values are multiples of 64.
#define GEMM_SEG(PAH, PAL, LEN, BOFF)                                                   \
  for (int kk = 0; kk < (LEN); kk += 64) {                                              \
    const short8 ahi0 = *(const short8*)((PAH) + kk);                                   \
    const short8 alo0 = *(const short8*)((PAL) + kk);                                   \
    const short8 ahi1 = *(const short8*)((PAH) + kk + 32);                              \
    const short8 alo1 = *(const short8*)((PAL) + kk + 32);                              \
    const short8 bhi0 = *(const short8*)(ldsHI + rowb * rowE + (BOFF) + kk + kof);      \
    const short8 blo0 = *(const short8*)(ldsLO + rowb * rowE + (BOFF) + kk + kof);      \
    const short8 bhi1 = *(const short8*)(ldsHI + rowb * rowE + (BOFF) + kk + 32 + kof); \
    const short8 blo1 = *(const short8*)(ldsLO + rowb * rowE + (BOFF) + kk + 32 + kof); \
    ac0 = __builtin_amdgcn_mfma_f32_16x16x32_bf16(ahi0, bhi0, ac0, 0, 0, 0);            \
    ac1 = __builtin_amdgcn_mfma_f32_16x16x32_bf16(ahi0, blo0, ac1, 0, 0, 0);            \
    ac2 = __builtin_amdgcn_mfma_f32_16x16x32_bf16(alo0, bhi0, ac2, 0, 0, 0);            \
    ac3 = __builtin_amdgcn_mfma_f32_16x16x32_bf16(ahi1, bhi1, ac3, 0, 0, 0);            \
    ac4 = __builtin_amdgcn_mfma_f32_16x16x32_bf16(ahi1, blo1, ac4, 0, 0, 0);            \
    ac5 = __builtin_amdgcn_mfma_f32_16x16x32_bf16(alo1, bhi1, ac5, 0, 0, 0);            \
  }

  for (int t = 0; t < TT; ++t) {
    // ---- wait for producers: relaxed spins, then ONE acquire (single inv)
    if (tid == 0) {
      if (t > 0)     spin_ge(&READY[layer * 256 + t - 1], 64);
      if (layer > 0) spin_ge(&READY[(layer - 1) * 256 + t], 64);
      if (t > 0 || layer > 0)   // one acquire: fences h data into view (L1/L2 inv)
        (void)__hip_atomic_load(&READY[layer * 256 + (t > 0 ? t - 1 : t)],
                                __ATOMIC_ACQUIRE, __HIP_MEMORY_SCOPE_AGENT);
    }
    __syncthreads();

    // ---- GEMM: C[64x16] += A[64xK] * W[16xK]^T, 3-pass bf16 split
    float4v ac0 = {0.f, 0.f, 0.f, 0.f}, ac1 = ac0, ac2 = ac0,
            ac3 = ac0, ac4 = ac0, ac5 = ac0;
    if (layer == 0) {
      const long xo = ((long)bglob * TT + t) * II + kof;
      GEMM_SEG(XHI + xo, XLO + xo, 128, 0);
      if (t > 0) {
        const long ho = ((long)(((t - 1) & 7) * 64 + bglob)) * 1024 + kof;
        GEMM_SEG(HHI + ho, HLO + ho, 1024, 128);
      }
    } else {
      const long hb = ((long)(((layer - 1) * 8 + (t & 7)) * 64 + bglob)) * 1024 + kof;
      GEMM_SEG(HHI + hb, HLO + hb, 1024, 0);
      if (t > 0) {
        const long hs = ((long)((layer * 8 + ((t - 1) & 7)) * 64 + bglob)) * 1024 + kof;
        GEMM_SEG(HHI + hs, HLO + hs, 1024, 1024);
      }
    }
    const float4v acc = ((ac0 + ac3) + (ac1 + ac4)) + (ac2 + ac5);

    // ---- back-pressure before overwriting h slot (t&7), which holds h[l][t-8]:
    // layer-l readers are implied done by READY[l][t-1]>=64 (monotone);
    // layer-(l+1) readers are at stage t-8.
    if (layer < 2 && t >= 8 && tid == 0)
      spin_ge(&READY[(layer + 1) * 256 + t - 8], 64);
    __syncthreads();   // also guarantees all waves' A-loads completed (GEMM done)

    // ---- tanh + split + store h tile (64 rows x 16 cols at n0)
    {
      unsigned short* dH = HHI + ((long)(layer * 8 + (t & 7)) * 64) * 1024;
      unsigned short* dL = HLO + ((long)(layer * 8 + (t & 7)) * 64) * 1024;
#pragma unroll
      for (int r = 0; r < 4; ++r) {
        const float v = tanhf(acc[r] + bcol);
        const unsigned short hh = f2bf(v);
        const long o = (long)(crow + r) * 1024 + n0 + rowb;
        dH[o] = hh;
        dL[o] = f2bf(v - bf2f(hh));
      }
    }
    __syncthreads();   // drains vmcnt for all waves => stores visible in L2

    if (tid == 0)      // one release: wbl2 (dirty set ~4 KB) + flag bump
      __hip_atomic_fetch_add(&READY[layer * 256 + t], 1, __ATOMIC_RELEASE,
                             __HIP_MEMORY_SCOPE_AGENT);
  }
#undef GEMM_SEG

  // ---- final FC (fp32) by block 0 once layer 2, t=255 is complete
  if (bid == 0) {
    if (tid == 0) {
      spin_ge(&READY[2 * 256 + 255], 64);
      (void)__hip_atomic_load(&READY[2 * 256 + 255], __ATOMIC_ACQUIRE,
                              __HIP_MEMORY_SCOPE_AGENT);
    }
    __syncthreads();
    if (tid < 128) {
      const int bb = tid >> 1, o = tid & 1;
      const unsigned short* hH = HHI + ((long)(2 * 8 + 7) * 64 + bb) * 1024;
      const unsigned short* hL = HLO + ((long)(2 * 8 + 7) * 64 + bb) * 1024;
      const float* w = fcw + o * 1024;
      float sum = fcb[o];
      for (int n = 0; n < 1024; n += 8) {
        const short8 vh = *(const short8*)(hH + n);
        const short8 vl = *(const short8*)(hL + n);
#pragma unroll
        for (int j = 0; j < 8; ++j)
          sum += (bf2f((unsigned short)vh[j]) + bf2f((unsigned short)vl[j])) * w[n + j];
      }
      out[bb * 2 + o] = sum;
    }
  }
}

extern "C" void kernel_launch(void* const* d_in, const int* in_sizes, int n_in,
                              void* d_out, int out_size, void* d_ws, size_t ws_size,
                              hipStream_t stream)
{
  using namespace rnncfg;
  const float* x   = (const float*)d_in[0];
  const float* wx0 = (const float*)d_in[1];
  const float* bx0 = (const float*)d_in[2];
  const float* wh0 = (const float*)d_in[3];
  const float* bh0 = (const float*)d_in[4];
  const float* wx  = (const float*)d_in[5];
  const float* bx  = (const float*)d_in[6];
  const float* wh  = (const float*)d_in[7];
  const float* bh  = (const float*)d_in[8];
  const float* fcw = (const float*)d_in[9];
  const float* fcb = (const float*)d_in[10];
  char* ws = (char*)d_ws;
  float* out = (float*)d_out;

  if (ws_size < (size_t)WS_NEED) return;

  hipFuncSetAttribute(reinterpret_cast<const void*>(rnn_pipeline_kernel),
                      hipFuncAttributeMaxDynamicSharedMemorySize, SMEM_BYTES);

  rnn_prep_kernel<<<dim3(1024), dim3(256), 0, stream>>>(
      x, wx0, bx0, wh0, bh0, wx, bx, wh, bh, ws);
  rnn_pipeline_kernel<<<dim3(192), dim3(256), SMEM_BYTES, stream>>>(
      ws, fcw, fcb, out);
}

// Round 4
// 5050.735 us; speedup vs baseline: 3.1338x; 1.5306x over previous
//
#include <hip/hip_runtime.h>

// SimpleRNN (B=64,T=256,I=128,H=1024,L=3,O=2) — persistent pipelined MFMA kernel, v4.
//
// v3 post-mortem (7.7ms): per-stage agent-scope acquire/release fences compile
// to buffer_inv / buffer_wbl2 full-L2 cache walks (WRITE_SIZE==all h-writes,
// FETCH==per-stage h refetch proved it), plus 8.6e7 LDS bank-conflict cycles.
//
// v4: ZERO cache-maintenance ops. h data moves via per-instruction
// device-coherent accesses (global_load/store_dwordx4 sc0 sc1 -> L3 coherence
// point). Flags are RELAXED agent atomics only (v3 proved visibility).
// Producer order: h-stores -> __syncthreads (vmcnt drain) -> relaxed flag add.
// B weights live in VGPRs (wave k-split, 128 VGPR/lane held across all 256
// steps) -> no ds_read in hot loop, no bank conflicts. LDS = 20KB fp32 partial
// buffer for the 4-wave reduction (stride-20 rows, conflict-free).
// Block = (layer, 16-col group); 192 blocks, 1 block/CU; all resident.

typedef __attribute__((ext_vector_type(8))) short short8;
typedef __attribute__((ext_vector_type(4))) float float4v;
typedef __attribute__((ext_vector_type(4))) unsigned short ushort4v;

#define DEVFN static __device__ __forceinline__

template<int N> struct IC { static constexpr int value = N; };

// Device-coherent 16B load/store: sc0 sc1 -> bypass L1/L2, access L3 point.
#define GLD(dst, ptr) \
  asm volatile("global_load_dwordx4 %0, %1, off sc0 sc1" : "=v"(dst) : "v"(ptr))
#define GST(ptr, val) \
  asm volatile("global_store_dwordx2 %0, %1, off sc0 sc1" :: "v"(ptr), "v"(val) : "memory")
#define GDRAIN() do { asm volatile("s_waitcnt vmcnt(0)" ::: "memory"); \
                      __builtin_amdgcn_sched_barrier(0); } while (0)

DEVFN unsigned short f2bf(float f) {           // fp32 -> bf16 bits, RNE
  unsigned int u = __float_as_uint(f);
  u += 0x7FFFu + ((u >> 16) & 1u);
  return (unsigned short)(u >> 16);
}
DEVFN float bf2f(unsigned short h) { return __uint_as_float(((unsigned int)h) << 16); }

DEVFN void spin_ge(int* p, int want) {         // relaxed poll; atomics at L3
  while (__hip_atomic_load(p, __ATOMIC_RELAXED, __HIP_MEMORY_SCOPE_AGENT) < want)
    __builtin_amdgcn_s_sleep(1);
}

namespace rnncfg {
constexpr int  TT = 256, HH = 1024;
constexpr long WELEMS = 1024L * 1152 + 2L * 1024 * 2048;   // concat [Wx|Wh], 3 layers
constexpr long XELEMS = 64L * 256 * 128;
constexpr long HELEMS = 3L * 8 * 64 * HH;                  // h ring: 3 layers x 8 slots

constexpr long OFF_WHI  = 0;
constexpr long OFF_WLO  = OFF_WHI + WELEMS * 2;
constexpr long OFF_XHI  = OFF_WLO + WELEMS * 2;
constexpr long OFF_XLO  = OFF_XHI + XELEMS * 2;
constexpr long OFF_HHI  = OFF_XLO + XELEMS * 2;
constexpr long OFF_HLO  = OFF_HHI + HELEMS * 2;
constexpr long OFF_BIAS = OFF_HLO + HELEMS * 2;
constexpr long OFF_CNT  = OFF_BIAS + 3L * HH * 4;
constexpr long N_CNT    = 768;                             // READY[3][256]
constexpr long WS_NEED  = OFF_CNT + N_CNT * 4;             // ~36.2 MB
}

__global__ __launch_bounds__(256) void rnn_prep_kernel(
    const float* __restrict__ x,
    const float* __restrict__ wx0, const float* __restrict__ bx0,
    const float* __restrict__ wh0, const float* __restrict__ bh0,
    const float* __restrict__ wx,  const float* __restrict__ bx,
    const float* __restrict__ wh,  const float* __restrict__ bh,
    char* __restrict__ ws)
{
  using namespace rnncfg;
  unsigned short* WHI = (unsigned short*)(ws + OFF_WHI);
  unsigned short* WLO = (unsigned short*)(ws + OFF_WLO);
  unsigned short* XHI = (unsigned short*)(ws + OFF_XHI);
  unsigned short* XLO = (unsigned short*)(ws + OFF_XLO);
  float* BIAS = (float*)(ws + OFF_BIAS);
  int*   CNT  = (int*)(ws + OFF_CNT);
  const long i0 = (long)blockIdx.x * blockDim.x + threadIdx.x;
  const long st = (long)gridDim.x * blockDim.x;

  for (long i = i0; i < N_CNT; i += st) CNT[i] = 0;   // ws is 0xAA-poisoned

  for (long i = i0; i < 3 * HH; i += st) {            // fused bias = bx + bh
    int l = (int)(i >> 10), n = (int)(i & 1023);
    BIAS[i] = (l == 0) ? (bx0[n] + bh0[n]) : (bx[(l - 1) * HH + n] + bh[(l - 1) * HH + n]);
  }
  for (long i = i0; i < XELEMS; i += st) {            // x -> bf16 hi/lo
    float v = x[i];
    unsigned short h = f2bf(v);
    XHI[i] = h; XLO[i] = f2bf(v - bf2f(h));
  }
  for (long i = i0; i < WELEMS; i += st) {            // concat [Wx|Wh] -> bf16 hi/lo
    long j = i; int n, k; float v;
    if (j < 1179648L) {                               // layer 0: [1024][1152]
      n = (int)(j / 1152); k = (int)(j % 1152);
      v = (k < 128) ? wx0[n * 128 + k] : wh0[(long)n * 1024 + (k - 128)];
    } else if (j < 3276800L) {                        // layer 1: [1024][2048]
      j -= 1179648L; n = (int)(j / 2048); k = (int)(j % 2048);
      v = (k < 1024) ? wx[(long)n * 1024 + k] : wh[(long)n * 1024 + (k - 1024)];
    } else {                                          // layer 2: [1024][2048]
      j -= 3276800L; n = (int)(j / 2048); k = (int)(j % 2048);
      v = (k < 1024) ? wx[1048576L + (long)n * 1024 + k]
                     : wh[1048576L + (long)n * 1024 + (k - 1024)];
    }
    unsigned short h = f2bf(v);
    WHI[i] = h; WLO[i] = f2bf(v - bf2f(h));
  }
}

template<int L>
__device__ __forceinline__ void run_block(char* __restrict__ ws, int tid, int n0,
                                          float* __restrict__ pbuf)
{
  using namespace rnncfg;
  constexpr int  KL    = (L == 0) ? 1152 : 2048;
  constexpr int  NKS   = (L == 0) ? 9 : 16;       // k-steps of 32 per wave
  constexpr int  NKS0  = (L == 0) ? 1 : 8;        // t==0: skip h_self terms
  constexpr long LWOFF = (L == 0) ? 0L : ((L == 1) ? 1179648L : 3276800L);

  const unsigned short* WHI = (const unsigned short*)(ws + OFF_WHI);
  const unsigned short* WLO = (const unsigned short*)(ws + OFF_WLO);
  const unsigned short* XHI = (const unsigned short*)(ws + OFF_XHI);
  const unsigned short* XLO = (const unsigned short*)(ws + OFF_XLO);
  unsigned short* HHI = (unsigned short*)(ws + OFF_HHI);
  unsigned short* HLO = (unsigned short*)(ws + OFF_HLO);
  const float* BIAS = (const float*)(ws + OFF_BIAS);
  int* READY = (int*)(ws + OFF_CNT);

  const int lane = tid & 63, wv = tid >> 6;
  const int rowb = lane & 15;                 // B col within tile / A row within M-tile
  const int kof  = (lane >> 4) * 8;           // frag k sub-offset

  // ---- B fragments into VGPRs, held for all 256 steps (128 VGPR/lane).
  short8 bhi[NKS], blo[NKS];
#pragma unroll
  for (int ks = 0; ks < NKS; ++ks) {
    const int kw = (L == 0)
        ? (ks == 0 ? wv * 32 : 128 + wv * 256 + (ks - 1) * 32)
        : (ks < 8 ? wv * 256 + ks * 32 : 1024 + wv * 256 + (ks - 8) * 32);
    const long bo = LWOFF + (long)(n0 + rowb) * KL + kw + kof;
    bhi[ks] = *(const short8*)(WHI + bo);
    blo[ks] = *(const short8*)(WLO + bo);
  }

  int rowoff[4], xrow[4];
#pragma unroll
  for (int mt = 0; mt < 4; ++mt) {
    rowoff[mt] = (mt * 16 + rowb) * 1024;     // h layout [64][1024]
    xrow[mt]   = (mt * 16 + rowb) * 32768;    // x layout [64][256][128]
  }

  for (int t = 0; t < TT; ++t) {
    if (tid == 0) {
      if (t > 0) spin_ge(&READY[L * 256 + t - 1], 64);
      if (L > 0) spin_ge(&READY[(L - 1) * 256 + t], 64);
    }
    __syncthreads();

    const unsigned short* selfH = HHI + (L * 8 + ((t - 1) & 7)) * 65536;
    const unsigned short* selfL = HLO + (L * 8 + ((t - 1) & 7)) * 65536;
    const unsigned short* belowH = (L > 0) ? HHI + ((L - 1) * 8 + (t & 7)) * 65536 : nullptr;
    const unsigned short* belowL = (L > 0) ? HLO + ((L - 1) * 8 + (t & 7)) * 65536 : nullptr;
    const unsigned short* xH = XHI + t * 128;
    const unsigned short* xL = XLO + t * 128;

    float4v acc[4];
#pragma unroll
    for (int mt = 0; mt < 4; ++mt) acc[mt] = (float4v){0.f, 0.f, 0.f, 0.f};

    // GEMM over this wave's K-slice: batches of <=4 k-steps; 32 loads in
    // flight, one vmcnt(0) drain + sched_barrier per batch, then MFMAs.
    auto do_gemm = [&](auto nkc) {
      constexpr int NK = decltype(nkc)::value;
#pragma unroll
      for (int kb = 0; kb < NK; kb += 4) {
        constexpr int DUMMY = 0; (void)DUMMY;
        const int ke = (kb + 4 < NK) ? kb + 4 : NK;
        short8 ah[4][4], al[4][4];
#pragma unroll
        for (int ks = kb; ks < ((kb + 4 < NK) ? kb + 4 : NK); ++ks) {
#pragma unroll
          for (int mt = 0; mt < 4; ++mt) {
            const unsigned short *ph, *pl;
            if (L == 0) {
              if (ks == 0) { ph = xH + xrow[mt] + wv * 32 + kof;
                             pl = xL + xrow[mt] + wv * 32 + kof; }
              else { const int c = wv * 256 + (ks - 1) * 32 + kof;
                     ph = selfH + rowoff[mt] + c; pl = selfL + rowoff[mt] + c; }
            } else {
              const int c = wv * 256 + (ks & 7) * 32 + kof;
              if (ks < 8) { ph = belowH + rowoff[mt] + c; pl = belowL + rowoff[mt] + c; }
              else        { ph = selfH  + rowoff[mt] + c; pl = selfL  + rowoff[mt] + c; }
            }
            GLD(ah[ks - kb][mt], ph);
            GLD(al[ks - kb][mt], pl);
          }
        }
        GDRAIN();
#pragma unroll
        for (int ks = kb; ks < ((kb + 4 < NK) ? kb + 4 : NK); ++ks) {
#pragma unroll
          for (int mt = 0; mt < 4; ++mt) {
            acc[mt] = __builtin_amdgcn_mfma_f32_16x16x32_bf16(ah[ks - kb][mt], bhi[ks], acc[mt], 0, 0, 0);
            acc[mt] = __builtin_amdgcn_mfma_f32_16x16x32_bf16(ah[ks - kb][mt], blo[ks], acc[mt], 0, 0, 0);
            acc[mt] = __builtin_amdgcn_mfma_f32_16x16x32_bf16(al[ks - kb][mt], bhi[ks], acc[mt], 0, 0, 0);
          }
        }
        (void)ke;
      }
    };
    if (t == 0) do_gemm(IC<NKS0>{}); else do_gemm(IC<NKS>{});

    // ---- partial [64 x 16] to LDS (row stride 20 floats: conflict-benign)
#pragma unroll
    for (int mt = 0; mt < 4; ++mt)
#pragma unroll
      for (int r = 0; r < 4; ++r)
        pbuf[wv * 1280 + (mt * 16 + (lane >> 4) * 4 + r) * 20 + rowb] = acc[mt][r];

    // back-pressure: slot (t&7) holds h[L][t-8]; layer L+1 readers are at t-8.
    if (L < 2 && t >= 8 && tid == 0)
      spin_ge(&READY[(L + 1) * 256 + t - 8], 64);
    __syncthreads();

    // ---- reduce 4 waves + bias + tanh + split + device-coherent store
    {
      const int row = tid >> 2, c4 = (tid & 3) * 4;
      float4v s = *(const float4v*)(pbuf + row * 20 + c4);
      s += *(const float4v*)(pbuf + 1280 + row * 20 + c4);
      s += *(const float4v*)(pbuf + 2560 + row * 20 + c4);
      s += *(const float4v*)(pbuf + 3840 + row * 20 + c4);
      ushort4v vhi, vlo;
#pragma unroll
      for (int j = 0; j < 4; ++j) {
        const float v = tanhf(s[j] + BIAS[L * 1024 + n0 + c4 + j]);
        const unsigned short hh = f2bf(v);
        vhi[j] = hh; vlo[j] = f2bf(v - bf2f(hh));
      }
      const long o = (long)(L * 8 + (t & 7)) * 65536 + row * 1024 + n0 + c4;
      GST(HHI + o, vhi);
      GST(HLO + o, vlo);
    }
    __syncthreads();   // drains vmcnt for all waves: h at L3 before flag

    if (tid == 0)
      __hip_atomic_fetch_add(&READY[L * 256 + t], 1, __ATOMIC_RELAXED,
                             __HIP_MEMORY_SCOPE_AGENT);
  }
}

__global__ __launch_bounds__(256) void rnn_pipeline_kernel(
    char* __restrict__ ws, const float* __restrict__ fcw,
    const float* __restrict__ fcb, float* __restrict__ out)
{
  using namespace rnncfg;
  __shared__ float pbuf[4 * 1280];             // 20 KB
  const int tid = threadIdx.x, bid = blockIdx.x;
  const int layer = bid >> 6, n0 = (bid & 63) * 16;

  if (layer == 0)      run_block<0>(ws, tid, n0, pbuf);
  else if (layer == 1) run_block<1>(ws, tid, n0, pbuf);
  else                 run_block<2>(ws, tid, n0, pbuf);

  // ---- final FC (fp32) by block 0 once layer 2, t=255 is complete
  if (bid == 0) {
    int* READY = (int*)(ws + OFF_CNT);
    if (tid == 0) spin_ge(&READY[2 * 256 + 255], 64);
    __syncthreads();
    if (tid < 128) {
      const unsigned short* HHI = (const unsigned short*)(ws + OFF_HHI);
      const unsigned short* HLO = (const unsigned short*)(ws + OFF_HLO);
      const int bb = tid >> 1, o = tid & 1;
      const unsigned short* hH = HHI + (long)(2 * 8 + 7) * 65536 + (long)bb * 1024;
      const unsigned short* hL = HLO + (long)(2 * 8 + 7) * 65536 + (long)bb * 1024;
      const float* w = fcw + o * 1024;
      float sum = fcb[o];
      for (int n = 0; n < 1024; n += 32) {     // 8 coherent loads in flight, then drain
        short8 vh[4], vl[4];
#pragma unroll
        for (int q = 0; q < 4; ++q) { GLD(vh[q], hH + n + q * 8); GLD(vl[q], hL + n + q * 8); }
        GDRAIN();
#pragma unroll
        for (int q = 0; q < 4; ++q)
#pragma unroll
          for (int j = 0; j < 8; ++j)
            sum += (bf2f((unsigned short)vh[q][j]) + bf2f((unsigned short)vl[q][j]))
                   * w[n + q * 8 + j];
      }
      out[bb * 2 + o] = sum;
    }
  }
}

extern "C" void kernel_launch(void* const* d_in, const int* in_sizes, int n_in,
                              void* d_out, int out_size, void* d_ws, size_t ws_size,
                              hipStream_t stream)
{
  using namespace rnncfg;
  const float* x   = (const float*)d_in[0];
  const float* wx0 = (const float*)d_in[1];
  const float* bx0 = (const float*)d_in[2];
  const float* wh0 = (const float*)d_in[3];
  const float* bh0 = (const float*)d_in[4];
  const float* wx  = (const float*)d_in[5];
  const float* bx  = (const float*)d_in[6];
  const float* wh  = (const float*)d_in[7];
  const float* bh  = (const float*)d_in[8];
  const float* fcw = (const float*)d_in[9];
  const float* fcb = (const float*)d_in[10];
  char* ws = (char*)d_ws;
  float* out = (float*)d_out;

  if (ws_size < (size_t)WS_NEED) return;

  rnn_prep_kernel<<<dim3(1024), dim3(256), 0, stream>>>(
      x, wx0, bx0, wh0, bh0, wx, bx, wh, bh, ws);
  rnn_pipeline_kernel<<<dim3(192), dim3(256), 0, stream>>>(
      ws, fcw, fcb, out);
}

// Round 5
// 4069.059 us; speedup vs baseline: 3.8898x; 1.2413x over previous
//
#include <hip/hip_runtime.h>

// SimpleRNN (B=64,T=256,I=128,H=1024,L=3,O=2) — persistent pipelined MFMA, v5.
//
// v4 post-mortem (5.05 ms): L3-BW-bound. 64 consumer blocks/layer each read the
// FULL h (512 KB hi/lo) via uncacheable sc0sc1 loads = 32 MB/layer-stage
// = 24.6 GB total at ~4.9 TB/s. Sync protocol (relaxed flags + sc0sc1 data)
// proved cheap; redundancy is the cost.
//
// v5: output group = 64 cols (was 16) -> A-read redundancy /4 (8 MB/layer-stage).
// B too big for one block -> K split across Q=4 sibling blocks (B stays
// VGPR-resident: [64 cols][512 k] hi/lo = 128 VGPR/lane). Siblings write fp32
// partials (sc0sc1, L3); last arriver (ARR relaxed-atomic returns old==3)
// finishes: sum + bias + tanh + bf16 hi/lo h-store + READY bump. Intra-block:
// 4 waves k-split, reduced via 65-float-stride LDS pbuf (<=2-way banks).
// h ring depth 4; total WS 36.2 MB (< v1's proven 37.6 MB budget).
// 192 blocks, 1 block/CU (VGPR ~350), all resident; flags relaxed agent (L3);
// no XCD-placement assumptions (correctness per G16).

typedef __attribute__((ext_vector_type(8))) short short8;
typedef __attribute__((ext_vector_type(4))) float float4v;

#define DEVFN static __device__ __forceinline__

// Device-coherent (L3 point) 16B ops; no cache-maintenance instructions.
#define GLD(dst, ptr) \
  asm volatile("global_load_dwordx4 %0, %1, off sc0 sc1" : "=v"(dst) : "v"(ptr))
#define GST16(ptr, val) \
  asm volatile("global_store_dwordx4 %0, %1, off sc0 sc1" :: "v"(ptr), "v"(val) : "memory")
#define GDRAIN() do { asm volatile("s_waitcnt vmcnt(0)" ::: "memory"); \
                      __builtin_amdgcn_sched_barrier(0); } while (0)

DEVFN unsigned short f2bf(float f) {           // fp32 -> bf16 bits, RNE
  unsigned int u = __float_as_uint(f);
  u += 0x7FFFu + ((u >> 16) & 1u);
  return (unsigned short)(u >> 16);
}
DEVFN float bf2f(unsigned short h) { return __uint_as_float(((unsigned int)h) << 16); }

DEVFN void spin_ge(int* p, int want) {         // relaxed poll; atomics at L3
  while (__hip_atomic_load(p, __ATOMIC_RELAXED, __HIP_MEMORY_SCOPE_AGENT) < want)
    __builtin_amdgcn_s_sleep(1);
}

namespace rnncfg {
constexpr int  TT = 256, HH = 1024;
constexpr long WELEMS = 1024L * 1152 + 2L * 1024 * 2048;   // concat [Wx|Wh], 3 layers
constexpr long XELEMS = 64L * 256 * 128;
constexpr long HELEMS = 3L * 4 * 64 * HH;                  // h ring: 3 layers x 4 slots
constexpr long PELEMS = 48L * 4 * 4096;                    // partials [g][q][64][64] f32

constexpr long OFF_WHI  = 0;
constexpr long OFF_WLO  = OFF_WHI + WELEMS * 2;
constexpr long OFF_XHI  = OFF_WLO + WELEMS * 2;
constexpr long OFF_XLO  = OFF_XHI + XELEMS * 2;
constexpr long OFF_HHI  = OFF_XLO + XELEMS * 2;
constexpr long OFF_HLO  = OFF_HHI + HELEMS * 2;
constexpr long OFF_BIAS = OFF_HLO + HELEMS * 2;
constexpr long OFF_CNT  = OFF_BIAS + 3L * HH * 4;
constexpr long N_CNT    = 768 + 48L * 256;                 // READY[3][256], ARR[48][256]
constexpr long OFF_PART = OFF_CNT + N_CNT * 4;
constexpr long WS_NEED  = OFF_PART + PELEMS * 4;           // 36,240,384 B

constexpr int SMEM_BYTES = 4 * 64 * 65 * 4;                // pbuf: 66,560 B
}

__global__ __launch_bounds__(256) void rnn_prep_kernel(
    const float* __restrict__ x,
    const float* __restrict__ wx0, const float* __restrict__ bx0,
    const float* __restrict__ wh0, const float* __restrict__ bh0,
    const float* __restrict__ wx,  const float* __restrict__ bx,
    const float* __restrict__ wh,  const float* __restrict__ bh,
    char* __restrict__ ws)
{
  using namespace rnncfg;
  unsigned short* WHI = (unsigned short*)(ws + OFF_WHI);
  unsigned short* WLO = (unsigned short*)(ws + OFF_WLO);
  unsigned short* XHI = (unsigned short*)(ws + OFF_XHI);
  unsigned short* XLO = (unsigned short*)(ws + OFF_XLO);
  float* BIAS = (float*)(ws + OFF_BIAS);
  int*   CNT  = (int*)(ws + OFF_CNT);
  const long i0 = (long)blockIdx.x * blockDim.x + threadIdx.x;
  const long st = (long)gridDim.x * blockDim.x;

  for (long i = i0; i < N_CNT; i += st) CNT[i] = 0;   // ws is 0xAA-poisoned

  for (long i = i0; i < 3 * HH; i += st) {            // fused bias = bx + bh
    int l = (int)(i >> 10), n = (int)(i & 1023);
    BIAS[i] = (l == 0) ? (bx0[n] + bh0[n]) : (bx[(l - 1) * HH + n] + bh[(l - 1) * HH + n]);
  }
  for (long i = i0; i < XELEMS; i += st) {            // x -> bf16 hi/lo
    float v = x[i];
    unsigned short h = f2bf(v);
    XHI[i] = h; XLO[i] = f2bf(v - bf2f(h));
  }
  for (long i = i0; i < WELEMS; i += st) {            // concat [Wx|Wh] -> bf16 hi/lo
    long j = i; int n, k; float v;
    if (j < 1179648L) {                               // layer 0: [1024][1152]
      n = (int)(j / 1152); k = (int)(j % 1152);
      v = (k < 128) ? wx0[n * 128 + k] : wh0[(long)n * 1024 + (k - 128)];
    } else if (j < 3276800L) {                        // layer 1: [1024][2048]
      j -= 1179648L; n = (int)(j / 2048); k = (int)(j % 2048);
      v = (k < 1024) ? wx[(long)n * 1024 + k] : wh[(long)n * 1024 + (k - 1024)];
    } else {                                          // layer 2: [1024][2048]
      j -= 3276800L; n = (int)(j / 2048); k = (int)(j % 2048);
      v = (k < 1024) ? wx[1048576L + (long)n * 1024 + k]
                     : wh[1048576L + (long)n * 1024 + (k - 1024)];
    }
    unsigned short h = f2bf(v);
    WHI[i] = h; WLO[i] = f2bf(v - bf2f(h));
  }
}

#define MFMA(a, b, c) __builtin_amdgcn_mfma_f32_16x16x32_bf16((a), (b), (c), 0, 0, 0)

template<int L>
DEVFN void run_block(char* __restrict__ ws, int tid, int g, int cg, int q,
                     float* __restrict__ pbuf, int* __restrict__ sFlag)
{
  using namespace rnncfg;
  constexpr long LWOFF = (L == 0) ? 0L : ((L == 1) ? 1179648L : 3276800L);
  constexpr int  KL    = (L == 0) ? 1152 : 2048;

  const unsigned short* WHI = (const unsigned short*)(ws + OFF_WHI);
  const unsigned short* WLO = (const unsigned short*)(ws + OFF_WLO);
  const unsigned short* XHI = (const unsigned short*)(ws + OFF_XHI);
  const unsigned short* XLO = (const unsigned short*)(ws + OFF_XLO);
  unsigned short* HHI = (unsigned short*)(ws + OFF_HHI);
  unsigned short* HLO = (unsigned short*)(ws + OFF_HLO);
  const float* BIAS = (const float*)(ws + OFF_BIAS);
  int* READY = (int*)(ws + OFF_CNT);                 // [3][256], 16 finishers each
  int* ARR   = READY + 768;                          // [48][256], 4 siblings each
  float* PART = (float*)(ws + OFF_PART);

  const int lane = tid & 63, wv = tid >> 6;
  const int rowb = lane & 15;                        // A row / B col within a 16-tile
  const int kof  = (lane >> 4) * 8;                  // frag k sub-offset
  const int n0   = cg * 64;

  // ---- B fragments -> VGPRs, held for all 256 steps (normal cached loads).
  short8 bh[4][4], bl[4][4];      // [nt][ks]   (L0: ks 0..1 used for h part)
  short8 bxh[4], bxl[4];          // L0 q0 only: x part
  if constexpr (L == 0) {
#pragma unroll
    for (int nt = 0; nt < 4; ++nt) {
      const long wr = LWOFF + (long)(n0 + nt * 16 + rowb) * KL;
      if (q == 0) { bxh[nt] = *(const short8*)(WHI + wr + wv * 32 + kof);
                    bxl[nt] = *(const short8*)(WLO + wr + wv * 32 + kof); }
#pragma unroll
      for (int j = 0; j < 2; ++j) {
        const int kc = 128 + q * 256 + wv * 64 + j * 32 + kof;
        bh[nt][j] = *(const short8*)(WHI + wr + kc);
        bl[nt][j] = *(const short8*)(WLO + wr + kc);
      }
    }
  } else {
#pragma unroll
    for (int nt = 0; nt < 4; ++nt) {
      const long wr = LWOFF + (long)(n0 + nt * 16 + rowb) * KL;
#pragma unroll
      for (int ks = 0; ks < 4; ++ks) {
        const int kc = q * 512 + wv * 128 + ks * 32 + kof;
        bh[nt][ks] = *(const short8*)(WHI + wr + kc);
        bl[nt][ks] = *(const short8*)(WLO + wr + kc);
      }
    }
  }

  float* myP = PART + (long)(g * 4 + q) * 4096;
  int* arrp = ARR + g * 256;

  for (int t = 0; t < TT; ++t) {
    if (tid == 0) {
      if (t > 0) spin_ge(&READY[L * 256 + t - 1], 16);
      if (L > 0) spin_ge(&READY[(L - 1) * 256 + t], 16);
    }
    __syncthreads();

    const unsigned short* selfH = HHI + (long)(L * 4 + ((t - 1) & 3)) * 65536;
    const unsigned short* selfL = HLO + (long)(L * 4 + ((t - 1) & 3)) * 65536;

    float4v acc[4][4];
#pragma unroll
    for (int mt = 0; mt < 4; ++mt)
#pragma unroll
      for (int nt = 0; nt < 4; ++nt) acc[mt][nt] = (float4v){0.f, 0.f, 0.f, 0.f};

    if constexpr (L == 0) {
      // x part (q0 only, every t) + self-h part (t>0). One drain for all loads.
      short8 xh[4], xl[4], ah[4][2], al[4][2];
      if (q == 0) {
#pragma unroll
        for (int mt = 0; mt < 4; ++mt) {
          const long xo = ((long)(mt * 16 + rowb) * 256 + t) * 128 + wv * 32 + kof;
          xh[mt] = *(const short8*)(XHI + xo);
          xl[mt] = *(const short8*)(XLO + xo);
        }
      }
      if (t > 0) {
        const int kb = q * 256 + wv * 64 + kof;
#pragma unroll
        for (int mt = 0; mt < 4; ++mt) {
          const int ao = (mt * 16 + rowb) * 1024 + kb;
#pragma unroll
          for (int j = 0; j < 2; ++j) { GLD(ah[mt][j], selfH + ao + j * 32);
                                        GLD(al[mt][j], selfL + ao + j * 32); }
        }
      }
      GDRAIN();
      if (q == 0) {
#pragma unroll
        for (int mt = 0; mt < 4; ++mt)
#pragma unroll
          for (int nt = 0; nt < 4; ++nt) {
            acc[mt][nt] = MFMA(xh[mt], bxh[nt], acc[mt][nt]);
            acc[mt][nt] = MFMA(xh[mt], bxl[nt], acc[mt][nt]);
            acc[mt][nt] = MFMA(xl[mt], bxh[nt], acc[mt][nt]);
          }
      }
      if (t > 0) {
#pragma unroll
        for (int j = 0; j < 2; ++j)
#pragma unroll
          for (int mt = 0; mt < 4; ++mt)
#pragma unroll
            for (int nt = 0; nt < 4; ++nt) {
              acc[mt][nt] = MFMA(ah[mt][j], bh[nt][j], acc[mt][nt]);
              acc[mt][nt] = MFMA(ah[mt][j], bl[nt][j], acc[mt][nt]);
              acc[mt][nt] = MFMA(al[mt][j], bh[nt][j], acc[mt][nt]);
            }
      }
    } else {
      // q0,q1: below-h slice; q2,q3: self-h slice (skipped at t==0).
      if (!(t == 0 && q >= 2)) {
        const unsigned short* AH = (q < 2)
            ? HHI + (long)((L - 1) * 4 + (t & 3)) * 65536 : selfH;
        const unsigned short* AL = (q < 2)
            ? HLO + (long)((L - 1) * 4 + (t & 3)) * 65536 : selfL;
        const int kb = (q & 1) * 512 + wv * 128 + kof;
        short8 ah[4][4], al[4][4];
#pragma unroll
        for (int mt = 0; mt < 4; ++mt) {
          const int ao = (mt * 16 + rowb) * 1024 + kb;
#pragma unroll
          for (int ks = 0; ks < 4; ++ks) { GLD(ah[mt][ks], AH + ao + ks * 32);
                                           GLD(al[mt][ks], AL + ao + ks * 32); }
        }
        GDRAIN();
#pragma unroll
        for (int ks = 0; ks < 4; ++ks)
#pragma unroll
          for (int mt = 0; mt < 4; ++mt)
#pragma unroll
            for (int nt = 0; nt < 4; ++nt) {
              acc[mt][nt] = MFMA(ah[mt][ks], bh[nt][ks], acc[mt][nt]);
              acc[mt][nt] = MFMA(ah[mt][ks], bl[nt][ks], acc[mt][nt]);
              acc[mt][nt] = MFMA(al[mt][ks], bh[nt][ks], acc[mt][nt]);
            }
      }
    }

    // ---- intra-block reduce: 4 waves -> pbuf (stride 65 floats, <=2-way banks)
#pragma unroll
    for (int mt = 0; mt < 4; ++mt)
#pragma unroll
      for (int nt = 0; nt < 4; ++nt)
#pragma unroll
        for (int r = 0; r < 4; ++r)
          pbuf[wv * 4160 + (mt * 16 + (lane >> 4) * 4 + r) * 65 + nt * 16 + rowb]
              = acc[mt][nt][r];
    __syncthreads();

    // ---- block partial [64][64] f32 -> L3 (sc0sc1), then arrival counter
    {
      const int prow = tid >> 2, pc0 = (tid & 3) * 16;
#pragma unroll
      for (int cq = 0; cq < 4; ++cq) {
        float4v s = *(const float4v*)(pbuf +        prow * 65 + pc0 + cq * 4);
        s += *(const float4v*)(pbuf + 4160 + prow * 65 + pc0 + cq * 4);
        s += *(const float4v*)(pbuf + 8320 + prow * 65 + pc0 + cq * 4);
        s += *(const float4v*)(pbuf + 12480 + prow * 65 + pc0 + cq * 4);
        GST16(myP + prow * 64 + pc0 + cq * 4, s);
      }
    }
    GDRAIN();
    __syncthreads();
    if (tid == 0) {
      const int old = __hip_atomic_fetch_add(&arrp[t], 1, __ATOMIC_RELAXED,
                                             __HIP_MEMORY_SCOPE_AGENT);
      *sFlag = (old == 3);                     // last arriver finishes
    }
    __syncthreads();

    if (*sFlag) {
      // back-pressure: h slot (t&3) holds h[L][t-4]; its layer-(L+1) readers
      // finish stage t-4 when READY[L+1][t-4]==16. Same-layer readers are
      // covered by READY[L][t-1] monotonicity.
      if (tid == 0 && L < 2 && t >= 4) spin_ge(&READY[(L + 1) * 256 + t - 4], 16);
      __syncthreads();

      const int prow = tid >> 2, pc0 = (tid & 3) * 16;
      const float* P0 = PART + (long)(g * 4) * 4096 + prow * 64 + pc0;
      float4v pa[4][4];                        // [q][cq]
#pragma unroll
      for (int qq = 0; qq < 4; ++qq)
#pragma unroll
        for (int cq = 0; cq < 4; ++cq)
          GLD(pa[qq][cq], P0 + qq * 4096 + cq * 4);
      GDRAIN();

      unsigned short* dH = HHI + (long)(L * 4 + (t & 3)) * 65536 + prow * 1024 + n0 + pc0;
      unsigned short* dL = HLO + (long)(L * 4 + (t & 3)) * 65536 + prow * 1024 + n0 + pc0;
      short8 vh[2], vl[2];
#pragma unroll
      for (int cq = 0; cq < 4; ++cq) {
        const float4v s = (pa[0][cq] + pa[1][cq]) + (pa[2][cq] + pa[3][cq]);
#pragma unroll
        for (int j = 0; j < 4; ++j) {
          const float v = tanhf(s[j] + BIAS[L * 1024 + n0 + pc0 + cq * 4 + j]);
          const unsigned short hh = f2bf(v);
          vh[cq >> 1][(cq & 1) * 4 + j] = (short)hh;
          vl[cq >> 1][(cq & 1) * 4 + j] = (short)f2bf(v - bf2f(hh));
        }
      }
      GST16(dH, vh[0]); GST16(dH + 8, vh[1]);
      GST16(dL, vl[0]); GST16(dL + 8, vl[1]);
      GDRAIN();
      __syncthreads();
      if (tid == 0)
        __hip_atomic_fetch_add(&READY[L * 256 + t], 1, __ATOMIC_RELAXED,
                               __HIP_MEMORY_SCOPE_AGENT);
    }
  }
}

__global__ __launch_bounds__(256, 1) void rnn_pipeline_kernel(
    char* __restrict__ ws, const float* __restrict__ fcw,
    const float* __restrict__ fcb, float* __restrict__ out)
{
  using namespace rnncfg;
  extern __shared__ float pbuf[];              // 4*64*65 floats
  __shared__ int sFlag;
  const int tid = threadIdx.x, bid = blockIdx.x;

  // bid -> (group g in [0,48), sibling q in [0,4)); g -> layer, col-group.
  const int xcd = bid & 7, s = bid >> 3;
  const int q = s & 3, gslot = s >> 2;
  const int g = gslot * 8 + xcd;
  const int layer = g >> 4, cg = g & 15;

  if (layer == 0)      run_block<0>(ws, tid, g, cg, q, pbuf, &sFlag);
  else if (layer == 1) run_block<1>(ws, tid, g, cg, q, pbuf, &sFlag);
  else                 run_block<2>(ws, tid, g, cg, q, pbuf, &sFlag);

  // ---- final FC (fp32) by block 0 once layer 2, t=255 is complete
  if (bid == 0) {
    int* READY = (int*)(ws + OFF_CNT);
    if (tid == 0) spin_ge(&READY[2 * 256 + 255], 16);
    __syncthreads();
    if (tid < 128) {
      const unsigned short* HHI = (const unsigned short*)(ws + OFF_HHI);
      const unsigned short* HLO = (const unsigned short*)(ws + OFF_HLO);
      const int bb = tid >> 1, o = tid & 1;
      const unsigned short* hH = HHI + (long)(2 * 4 + 3) * 65536 + (long)bb * 1024;
      const unsigned short* hL = HLO + (long)(2 * 4 + 3) * 65536 + (long)bb * 1024;
      const float* w = fcw + o * 1024;
      float sum = fcb[o];
      for (int n = 0; n < 1024; n += 32) {     // 8 coherent loads in flight
        short8 vh[4], vl[4];
#pragma unroll
        for (int qq = 0; qq < 4; ++qq) { GLD(vh[qq], hH + n + qq * 8);
                                         GLD(vl[qq], hL + n + qq * 8); }
        GDRAIN();
#pragma unroll
        for (int qq = 0; qq < 4; ++qq)
#pragma unroll
          for (int j = 0; j < 8; ++j)
            sum += (bf2f((unsigned short)vh[qq][j]) + bf2f((unsigned short)vl[qq][j]))
                   * w[n + qq * 8 + j];
      }
      out[bb * 2 + o] = sum;
    }
  }
}

extern "C" void kernel_launch(void* const* d_in, const int* in_sizes, int n_in,
                              void* d_out, int out_size, void* d_ws, size_t ws_size,
                              hipStream_t stream)
{
  using namespace rnncfg;
  const float* x   = (const float*)d_in[0];
  const float* wx0 = (const float*)d_in[1];
  const float* bx0 = (const float*)d_in[2];
  const float* wh0 = (const float*)d_in[3];
  const float* bh0 = (const float*)d_in[4];
  const float* wx  = (const float*)d_in[5];
  const float* bx  = (const float*)d_in[6];
  const float* wh  = (const float*)d_in[7];
  const float* bh  = (const float*)d_in[8];
  const float* fcw = (const float*)d_in[9];
  const float* fcb = (const float*)d_in[10];
  char* ws = (char*)d_ws;
  float* out = (float*)d_out;

  if (ws_size < (size_t)WS_NEED) return;

  hipFuncSetAttribute(reinterpret_cast<const void*>(rnn_pipeline_kernel),
                      hipFuncAttributeMaxDynamicSharedMemorySize, SMEM_BYTES);

  rnn_prep_kernel<<<dim3(1024), dim3(256), 0, stream>>>(
      x, wx0, bx0, wh0, bh0, wx, bx, wh, bh, ws);
  rnn_pipeline_kernel<<<dim3(192), dim3(256), SMEM_BYTES, stream>>>(
      ws, fcw, fcb, out);
}